// Round 6
// baseline (1600.123 us; speedup 1.0000x reference)
//
#include <hip/hip_runtime.h>

#define D_DIM 2560
#define T_DIM 4096
#define B_DIM 4
#define H_DIM 10
#define DH 256
#define TW_DIM 4
#define M_DIM (B_DIM * T_DIM)   // 16384
#define CHUNKS 64
#define TC (T_DIM / CHUNKS)     // 64

typedef _Float16 f16;
typedef __attribute__((ext_vector_type(8))) _Float16 f16x8;
typedef __attribute__((ext_vector_type(4))) _Float16 f16x4;
typedef __attribute__((ext_vector_type(2))) _Float16 f16x2;
typedef __attribute__((ext_vector_type(4))) float f32x4;
typedef __attribute__((ext_vector_type(2))) float f32x2;

// ---------------- convert f32 -> f16 (vectorized x4) ----------------
__global__ void cvt_f16_kernel(const float* __restrict__ in, f16* __restrict__ out, long n4) {
  long i = (long)blockIdx.x * blockDim.x + threadIdx.x;
  if (i >= n4) return;
  f32x4 v = ((const f32x4*)in)[i];
  f16x4 o;
  o[0] = (f16)v[0]; o[1] = (f16)v[1]; o[2] = (f16)v[2]; o[3] = (f16)v[3];
  ((f16x4*)out)[i] = o;
}

// ---------------- transpose + convert, 3 separate square sources ----------------
__global__ void transpose_cvt3_kernel(const float* __restrict__ s0, const float* __restrict__ s1,
                                      const float* __restrict__ s2, f16* __restrict__ out,
                                      int R, int C) {
  __shared__ float tile[32][33];
  const int z = blockIdx.z;
  const float* in = (z == 0) ? s0 : ((z == 1) ? s1 : s2);
  out += (long)z * R * C;
  int c0 = blockIdx.x * 32, r0 = blockIdx.y * 32;
  int tx = threadIdx.x, ty = threadIdx.y;
  for (int i = ty; i < 32; i += 8)
    tile[i][tx] = in[(long)(r0 + i) * C + (c0 + tx)];
  __syncthreads();
  for (int i = ty; i < 32; i += 8)
    out[(long)(c0 + i) * R + (r0 + tx)] = (f16)tile[tx][i];
}

// ---------------- transpose + convert, 2 batched sources (ig, ag) ----------------
__global__ void transpose_cvt2_kernel(const float* __restrict__ sa, const float* __restrict__ sb,
                                      f16* __restrict__ out, int R, int C, int half) {
  __shared__ float tile[32][33];
  const int z = blockIdx.z;
  const float* in = (z < half) ? (sa + (long)z * R * C) : (sb + (long)(z - half) * R * C);
  out += (long)z * R * C;
  int c0 = blockIdx.x * 32, r0 = blockIdx.y * 32;
  int tx = threadIdx.x, ty = threadIdx.y;
  for (int i = ty; i < 32; i += 8)
    tile[i][tx] = in[(long)(r0 + i) * C + (c0 + tx)];
  __syncthreads();
  for (int i = ty; i < 32; i += 8)
    out[(long)(c0 + i) * R + (r0 + tx)] = (f16)tile[tx][i];
}

// ---------------- async global -> LDS, 16B per lane ----------------
__device__ __forceinline__ void async_cp16(const void* g, void* l) {
  __builtin_amdgcn_global_load_lds(
      (const __attribute__((address_space(1))) unsigned int*)g,
      (__attribute__((address_space(3))) unsigned int*)l, 16, 0, 0);
}

__device__ __forceinline__ float fast_sigmoid(float v) {
  return 1.f / (1.f + __expf(-v));
}

// =====================================================================
// Barrier-light 256x256 GEMM. BK=64, 2 LDS buffers (64KB each), ONE
// vmcnt(0)+s_barrier per K-step (no mid-barriers). Per wave per K-step:
// 3 clusters {ds_reads, counted lgkmcnt + sched_barrier, setprio, MFMA}.
// Waves skew within the step -> LDS-read pipe overlaps MFMA pipe across
// waves (separate pipes, m114). Stages for step s+1 issue at step-s start
// (A) and mid-step (B); vmcnt(0) at step end is nearly free (>=1000cy in
// flight). Buffer WAR: target buf held tile s-1, last read drained by the
// end-of-(s-1) barrier. Swizzle unchanged from R4 (conflicts == 0).
//
// FUSED=1: N-concatenated dual output ([Wy|Wx]): cols<2560 -> gelu -> C0,
// cols>=2560 -> plain -> C1 (block-uniform split; BN=256 | 2560).
// =====================================================================
#define BM2 256
#define BN2 256

template<int FUSED, int OUT16>
__global__ __launch_bounds__(512, 2)
void gemm256_kernel(const f16* __restrict__ A, long ldA,
                    const f16* __restrict__ Bt, long ldB,
                    const float* __restrict__ bias0, const float* __restrict__ bias1,
                    void* __restrict__ C0, void* __restrict__ C1,
                    long ldC, int K) {
  __shared__ __attribute__((aligned(16))) f16 smh[65536];  // 128 KiB
  const int tid = threadIdx.x;
  const int wave = tid >> 6;
  const int lane = tid & 63;
  const int wm = wave >> 2;      // 0..1 -> rows wm*128..+127
  const int wn = wave & 3;       // 0..3 -> cols wn*64..+63

  // ---- XCD-aware chunked block remap (nwg % 8 == 0 for both grids)
  const int nx_ = gridDim.x;
  const int nwg = nx_ * gridDim.y;
  int lid = blockIdx.y * nx_ + blockIdx.x;
  lid = (lid & 7) * (nwg >> 3) + (lid >> 3);
  const long bm = (long)(lid / nx_) * BM2;
  const long bn = (long)(lid % nx_) * BN2;

  // ---- staging geometry: instr covers 8 rows x 128B; wave w covers rows 16w..16w+15 (2 instr)
  const int rsub = lane >> 3;                     // 0..7
  const int gc8 = (((lane & 7) ^ rsub) & 7) * 8;  // swizzled global 16B-chunk (halfs)
  const f16* gA0 = A + (bm + wave * 16 + rsub) * ldA + gc8;
  const f16* gB0 = Bt + (bn + wave * 16 + rsub) * ldB + gc8;
  const int wls = wave * 1024;                    // lds halfs within half-tile

#define STG_A(buf, al, ko) do { \
  async_cp16(gA0 + ((al) * 128) * ldA + (ko), smh + (buf) * 32768 + (al) * 8192 + wls); \
  async_cp16(gA0 + ((al) * 128 + 8) * ldA + (ko), smh + (buf) * 32768 + (al) * 8192 + wls + 512); \
} while (0)
#define STG_B(buf, bl, ko) do { \
  async_cp16(gB0 + ((bl) * 128) * ldB + (ko), smh + (buf) * 32768 + 16384 + (bl) * 8192 + wls); \
  async_cp16(gB0 + ((bl) * 128 + 8) * ldB + (ko), smh + (buf) * 32768 + 16384 + (bl) * 8192 + wls + 512); \
} while (0)

  // ---- fragment-read geometry (reader compensates store swizzle)
  const int quad = lane >> 4, l16 = lane & 15;
  const int sw0 = ((quad ^ (l16 & 7)) & 7) * 8;        // h=0 chunk (halfs)
  const int sw1 = (((4 + quad) ^ (l16 & 7)) & 7) * 8;  // h=1 chunk

  f16x8 aL[4][2], aH[4][2], bF[4][2];
  f32x4 acc[8][4];
#pragma unroll
  for (int i = 0; i < 8; ++i)
#pragma unroll
    for (int j = 0; j < 4; ++j) {
      acc[i][j][0] = 0.f; acc[i][j][1] = 0.f; acc[i][j][2] = 0.f; acc[i][j][3] = 0.f;
    }

#define LD8(off) (*(const f16x8*)&smh[(off)])
#define MM(AX, MB, N0) do { _Pragma("unroll") for (int m_ = 0; m_ < 4; ++m_) \
  _Pragma("unroll") for (int n_ = 0; n_ < 2; ++n_) \
    acc[(MB) + m_][(N0) + n_] = __builtin_amdgcn_mfma_f32_16x16x32_f16(AX[m_][1], bF[(N0) + n_][1], \
      __builtin_amdgcn_mfma_f32_16x16x32_f16(AX[m_][0], bF[(N0) + n_][0], acc[(MB) + m_][(N0) + n_], 0, 0, 0), 0, 0, 0); \
} while (0)

// One K-step: reads buf BUF (tile S), stages tile S+1 into buf BUF^1.
#define KSTEP(BUF, S) do { \
  const long kn_ = (long)((S) + 1 < NT ? (S) + 1 : (S)) * 64; \
  const int aB_ = (BUF) * 32768 + wm * 8192 + l16 * 64; \
  const int bB_ = (BUF) * 32768 + 16384 + (wn >> 1) * 8192 + ((wn & 1) * 64 + l16) * 64; \
  STG_A(BUF ^ 1, 0, kn_); STG_A(BUF ^ 1, 1, kn_); \
  _Pragma("unroll") for (int m_ = 0; m_ < 4; ++m_) { \
    aL[m_][0] = LD8(aB_ + m_ * 1024 + sw0); aL[m_][1] = LD8(aB_ + m_ * 1024 + sw1); } \
  _Pragma("unroll") for (int n_ = 0; n_ < 2; ++n_) { \
    bF[n_][0] = LD8(bB_ + n_ * 1024 + sw0); bF[n_][1] = LD8(bB_ + n_ * 1024 + sw1); } \
  STG_B(BUF ^ 1, 0, kn_); \
  asm volatile("s_waitcnt lgkmcnt(0)" ::: "memory"); \
  __builtin_amdgcn_sched_barrier(0); \
  __builtin_amdgcn_s_setprio(1); \
  MM(aL, 0, 0); \
  __builtin_amdgcn_s_setprio(0); \
  _Pragma("unroll") for (int n_ = 2; n_ < 4; ++n_) { \
    bF[n_][0] = LD8(bB_ + n_ * 1024 + sw0); bF[n_][1] = LD8(bB_ + n_ * 1024 + sw1); } \
  _Pragma("unroll") for (int m_ = 0; m_ < 4; ++m_) { \
    aH[m_][0] = LD8(aB_ + 4096 + m_ * 1024 + sw0); aH[m_][1] = LD8(aB_ + 4096 + m_ * 1024 + sw1); } \
  STG_B(BUF ^ 1, 1, kn_); \
  asm volatile("s_waitcnt lgkmcnt(8)" ::: "memory"); \
  __builtin_amdgcn_sched_barrier(0); \
  __builtin_amdgcn_s_setprio(1); \
  MM(aL, 0, 2); \
  __builtin_amdgcn_s_setprio(0); \
  asm volatile("s_waitcnt lgkmcnt(0)" ::: "memory"); \
  __builtin_amdgcn_sched_barrier(0); \
  __builtin_amdgcn_s_setprio(1); \
  MM(aH, 4, 2); MM(aH, 4, 0); \
  __builtin_amdgcn_s_setprio(0); \
  asm volatile("s_waitcnt vmcnt(0)" ::: "memory"); \
  __builtin_amdgcn_s_barrier(); \
  __builtin_amdgcn_sched_barrier(0); \
} while (0)

  const int NT = K / 64;   // 40

  // ---- prologue: stage tile 0 into buf0, publish
  STG_A(0, 0, 0); STG_A(0, 1, 0); STG_B(0, 0, 0); STG_B(0, 1, 0);
  asm volatile("s_waitcnt vmcnt(0)" ::: "memory");
  __builtin_amdgcn_s_barrier();
  __builtin_amdgcn_sched_barrier(0);

#pragma unroll 1
  for (int s2 = 0; s2 < NT; s2 += 2) {
    KSTEP(0, s2);
    KSTEP(1, s2 + 1);
  }

  // ---- epilogue: C/D layout col=lane&15, row=(lane>>4)*4+reg
  // FUSED: block-uniform output split at col 2560
  const float* bz = bias0;
  f16* c16 = (f16*)C0;
  float* c32 = (float*)C0;
  long cb = bn;
  bool doGelu = false;
  if (FUSED) {
    const bool h2 = (bn >= 2560);
    bz = h2 ? bias1 : bias0;
    c16 = h2 ? (f16*)C1 : (f16*)C0;
    cb = h2 ? bn - 2560 : bn;
    doGelu = !h2;
  }
#pragma unroll
  for (int i = 0; i < 8; ++i) {
    const long row0 = bm + wm * 128 + i * 16 + quad * 4;
#pragma unroll
    for (int j = 0; j < 4; ++j) {
      const long colW = cb + wn * 64 + j * 16 + l16;
      const float bv = bz[colW];
#pragma unroll
      for (int r = 0; r < 4; ++r) {
        const long row = row0 + r;
        float v = acc[i][j][r] + bv;
        if (FUSED) {
          if (doGelu) {
            const float u = v;
            const float tt = 0.7978845608028654f * (u + 0.044715f * u * u * u);
            v = u * fast_sigmoid(2.f * tt);   // gelu tanh approx
          }
          c16[row * ldC + colW] = (f16)v;
        } else if (OUT16) {
          c16[row * ldC + colW] = (f16)v;
        } else {
          c32[row * ldC + colW] = v;
        }
      }
    }
  }
#undef STG_A
#undef STG_B
#undef LD8
#undef MM
#undef KSTEP
}

// =====================================================================
// Fused gate GEMMs: gate_x/gate_a sigmoid + RG-LRU elementwise -> a16, nx16
// =====================================================================
#define BM 128
#define BN 128
#define BK 32

__global__ __launch_bounds__(256, 2)
void gemm_gates_kernel(const f16* __restrict__ A, long ldA,
                       const f16* __restrict__ igt, const f16* __restrict__ agt,
                       const float* __restrict__ igb, const float* __restrict__ agb,
                       const float* __restrict__ apar, const int* __restrict__ segp,
                       f16* __restrict__ aOut, f16* __restrict__ nxOut, int K) {
  __shared__ __attribute__((aligned(16))) f16 As[BM * BK];
  __shared__ __attribute__((aligned(16))) f16 B1s[BN * BK];
  __shared__ __attribute__((aligned(16))) f16 B2s[BN * BK];
  const int tid = threadIdx.x;
  const int wave = tid >> 6;
  const int lane = tid & 63;
  const int wm = wave >> 1, wn = wave & 1;
  const long bm = (long)blockIdx.y * BM;
  const long bn = (long)blockIdx.x * BN;
  const int z = blockIdx.z;
  const f16* Az = A + (long)z * DH;                  // column offset into [M,D]
  const f16* B1 = igt + (long)z * DH * DH;
  const f16* B2 = agt + (long)z * DH * DH;
  const float* b1 = igb + (long)z * DH;
  const float* b2 = agb + (long)z * DH;
  const long cColOff = (long)z * DH;

  const int sRow = wave * 32 + (lane >> 2);
  const int sCol = ((lane & 3) ^ (sRow & 3) ^ ((sRow >> 2) & 3)) * 8;  // halfs
  const f16* gA = Az + (bm + sRow) * ldA + sCol;
  const f16* gB1 = B1 + (bn + sRow) * (long)K + sCol;
  const f16* gB2 = B2 + (bn + sRow) * (long)K + sCol;
  f16* lA = As + wave * 1024;
  f16* lB1 = B1s + wave * 1024;
  f16* lB2 = B2s + wave * 1024;

  f32x4 accI[4][4], accA[4][4];
#pragma unroll
  for (int i = 0; i < 4; ++i)
#pragma unroll
    for (int j = 0; j < 4; ++j) {
      accI[i][j][0] = 0.f; accI[i][j][1] = 0.f; accI[i][j][2] = 0.f; accI[i][j][3] = 0.f;
      accA[i][j][0] = 0.f; accA[i][j][1] = 0.f; accA[i][j][2] = 0.f; accA[i][j][3] = 0.f;
    }

  const int quad = lane >> 4, l16 = lane & 15;
  const int rswz = (quad ^ (l16 & 3) ^ ((l16 >> 2) & 3)) * 8;

  for (int k0 = 0; k0 < K; k0 += BK) {
    async_cp16(gA, lA);
    async_cp16(gA + 16 * ldA, lA + 512);
    async_cp16(gB1, lB1);
    async_cp16(gB1 + 16 * (long)K, lB1 + 512);
    async_cp16(gB2, lB2);
    async_cp16(gB2 + 16 * (long)K, lB2 + 512);
    gA += BK; gB1 += BK; gB2 += BK;
    __syncthreads();
    f16x8 af[4], bf1[4], bf2[4];
#pragma unroll
    for (int i = 0; i < 4; ++i) {
      af[i]  = *(const f16x8*)&As[(wm * 64 + i * 16 + l16) * BK + rswz];
      bf1[i] = *(const f16x8*)&B1s[(wn * 64 + i * 16 + l16) * BK + rswz];
      bf2[i] = *(const f16x8*)&B2s[(wn * 64 + i * 16 + l16) * BK + rswz];
    }
#pragma unroll
    for (int i = 0; i < 4; ++i)
#pragma unroll
      for (int j = 0; j < 4; ++j) {
        accI[i][j] = __builtin_amdgcn_mfma_f32_16x16x32_f16(af[i], bf1[j], accI[i][j], 0, 0, 0);
        accA[i][j] = __builtin_amdgcn_mfma_f32_16x16x32_f16(af[i], bf2[j], accA[i][j], 0, 0, 0);
      }
    __syncthreads();
  }

#pragma unroll
  for (int i = 0; i < 4; ++i) {
    const long row0 = bm + wm * 64 + i * 16 + quad * 4;
#pragma unroll
    for (int j = 0; j < 4; ++j) {
      const long colIn = bn + wn * 64 + j * 16 + l16;
      const long colG = cColOff + colIn;
      const float bv1 = b1[colIn];
      const float bv2 = b2[colIn];
      const float sp = log1pf(__expf(apar[colG]));
#pragma unroll
      for (int r = 0; r < 4; ++r) {
        const long row = row0 + r;
        const float gx = fast_sigmoid(accI[i][j][r] + bv1);
        const float ga = fast_sigmoid(accA[i][j][r] + bv2);
        const float log_a = -8.f * ga * sp;
        float a = __expf(log_a);
        float mult = sqrtf(fmaxf(1.f - __expf(2.f * log_a), 0.f));
        if (segp[row] == 0) { a = 0.f; mult = 1.f; }
        const long cidx = row * D_DIM + colG;
        const float cv = (float)A[row * ldA + colG];   // conv value
        aOut[cidx] = (f16)a;
        nxOut[cidx] = (f16)(cv * gx * mult);
      }
    }
  }
}

// ---------------- causal depthwise conv (TW=4), f16 in -> f16 out, x4 ----------------
__global__ void conv_kernel(const f16* __restrict__ xb, const float* __restrict__ cw,
                            const float* __restrict__ cb, f16* __restrict__ out) {
  const int d4 = blockIdx.x * 128 + threadIdx.x;  // over D/4 = 640
  const int t = blockIdx.y;
  const int b = blockIdx.z;
  const long idx4 = ((long)b * T_DIM + t) * (D_DIM / 4) + d4;
  f32x4 acc = ((const f32x4*)cb)[d4];
#pragma unroll
  for (int i = 0; i < TW_DIM; ++i) {
    const int tt = t - (TW_DIM - 1) + i;
    if (tt >= 0) {
      f16x4 xv = ((const f16x4*)xb)[idx4 + (long)(i - (TW_DIM - 1)) * (D_DIM / 4)];
      f32x4 w = ((const f32x4*)cw)[i * (D_DIM / 4) + d4];
      acc[0] += w[0] * (float)xv[0];
      acc[1] += w[1] * (float)xv[1];
      acc[2] += w[2] * (float)xv[2];
      acc[3] += w[3] * (float)xv[3];
    }
  }
  f16x4 o;
  o[0] = (f16)acc[0]; o[1] = (f16)acc[1]; o[2] = (f16)acc[2]; o[3] = (f16)acc[3];
  ((f16x4*)out)[idx4] = o;
}

// ---------------- chunked scan: h_t = a_t h_{t-1} + x_t (x2 vectorized) ----------------
__global__ void scanA_kernel(const f16* __restrict__ a16, const f16* __restrict__ nx16,
                             float* __restrict__ Ac, float* __restrict__ Sc) {
  const int d2 = blockIdx.x * 256 + threadIdx.x;  // over D/2 = 1280
  const int c = blockIdx.y;
  const int b = blockIdx.z;
  long base2 = ((long)b * T_DIM + (long)c * TC) * (D_DIM / 2) + d2;
  float Ap0 = 1.f, Ap1 = 1.f, S0 = 0.f, S1 = 0.f;
  for (int t = 0; t < TC; ++t) {
    f16x2 av = ((const f16x2*)a16)[base2];
    f16x2 xv = ((const f16x2*)nx16)[base2];
    S0 = (float)av[0] * S0 + (float)xv[0];
    S1 = (float)av[1] * S1 + (float)xv[1];
    Ap0 *= (float)av[0];
    Ap1 *= (float)av[1];
    base2 += D_DIM / 2;
  }
  const long cidx2 = ((long)b * CHUNKS + c) * (D_DIM / 2) + d2;
  f32x2 av_; av_[0] = Ap0; av_[1] = Ap1;
  f32x2 sv_; sv_[0] = S0; sv_[1] = S1;
  ((f32x2*)Ac)[cidx2] = av_;
  ((f32x2*)Sc)[cidx2] = sv_;
}

__global__ void scanB_kernel(const float* __restrict__ Ac, const float* __restrict__ Sc,
                             float* __restrict__ He) {
  const int d = blockIdx.x * 256 + threadIdx.x;
  const int b = blockIdx.z;
  float h = 0.f;
  for (int c = 0; c < CHUNKS; ++c) {
    const long cidx = ((long)b * CHUNKS + c) * D_DIM + d;
    He[cidx] = h;  // h at entry of chunk c
    h = Ac[cidx] * h + Sc[cidx];
  }
}

__global__ void scanC_kernel(const f16* __restrict__ a16, const f16* __restrict__ nx16,
                             const float* __restrict__ He, const f16* __restrict__ y16,
                             f16* __restrict__ hy16) {
  const int d2 = blockIdx.x * 256 + threadIdx.x;
  const int c = blockIdx.y;
  const int b = blockIdx.z;
  long base2 = ((long)b * T_DIM + (long)c * TC) * (D_DIM / 2) + d2;
  f32x2 hv = ((const f32x2*)He)[((long)b * CHUNKS + c) * (D_DIM / 2) + d2];
  float h0 = hv[0], h1 = hv[1];
  for (int t = 0; t < TC; ++t) {
    f16x2 av = ((const f16x2*)a16)[base2];
    f16x2 xv = ((const f16x2*)nx16)[base2];
    f16x2 yv = ((const f16x2*)y16)[base2];
    h0 = (float)av[0] * h0 + (float)xv[0];
    h1 = (float)av[1] * h1 + (float)xv[1];
    f16x2 o;
    o[0] = (f16)(h0 * (float)yv[0]);
    o[1] = (f16)(h1 * (float)yv[1]);
    ((f16x2*)hy16)[base2] = o;
    base2 += D_DIM / 2;
  }
}

// ---------------- launch ----------------
extern "C" void kernel_launch(void* const* d_in, const int* in_sizes, int n_in,
                              void* d_out, int out_size, void* d_ws, size_t ws_size,
                              hipStream_t stream) {
  const float* x   = (const float*)d_in[0];
  const int*   segp= (const int*)d_in[1];
  const float* Wy  = (const float*)d_in[2];
  const float* by  = (const float*)d_in[3];
  const float* Wx  = (const float*)d_in[4];
  const float* bx  = (const float*)d_in[5];
  const float* cw  = (const float*)d_in[6];
  const float* cb  = (const float*)d_in[7];
  const float* ap  = (const float*)d_in[8];
  const float* igw = (const float*)d_in[9];
  const float* igb = (const float*)d_in[10];
  const float* agw = (const float*)d_in[11];
  const float* agb = (const float*)d_in[12];
  const float* Wo  = (const float*)d_in[13];
  const float* bo  = (const float*)d_in[14];
  float* out = (float*)d_out;
  char* ws = (char*)d_ws;

  const long MD = (long)M_DIM * D_DIM;  // 41,943,040
  f16*   x16    = (f16*)(ws + 0);          // dead after fused GEMM -> a16
  f16*   a16    = (f16*)(ws + 0);
  f16*   y16    = (f16*)(ws + MD * 2);     // live until scanC
  f16*   xb2    = (f16*)(ws + MD * 4);     // dead after conv -> hy16
  f16*   hy16   = (f16*)(ws + MD * 4);
  f16*   conv16 = (f16*)(ws + MD * 6);     // live until gates epilogue
  f16*   nx16   = (f16*)(ws + MD * 8);
  long off = MD * 10;
  f16* Wt  = (f16*)(ws + off); off += 3L * D_DIM * D_DIM * 2;   // Wyt,Wxt,Wot contiguous
  f16* igagt = (f16*)(ws + off); off += 20L * DH * DH * 2;      // igt(10) then agt(10)
  float* Ac = (float*)(ws + off); off += (long)B_DIM * CHUNKS * D_DIM * 4;
  float* Sc = (float*)(ws + off); off += (long)B_DIM * CHUNKS * D_DIM * 4;
  float* He = (float*)(ws + off); off += (long)B_DIM * CHUNKS * D_DIM * 4;
  f16* Wot = Wt + 2L * D_DIM * D_DIM;
  f16* igt = igagt;
  f16* agt = igagt + 10L * DH * DH;

  dim3 tb(32, 8);
  // 1. x -> f16
  cvt_f16_kernel<<<dim3((unsigned)(MD / 4 / 256)), 256, 0, stream>>>(x, x16, MD / 4);
  // 2. weight transposes -> [N,K] f16
  transpose_cvt3_kernel<<<dim3(80, 80, 3), tb, 0, stream>>>(Wy, Wx, Wo, Wt, D_DIM, D_DIM);
  transpose_cvt2_kernel<<<dim3(8, 8, 20), tb, 0, stream>>>(igw, agw, igagt, DH, DH, 10);
  // 3+4. fused: [y | xb] = x @ [Wy|Wx] + [by|bx]; gelu on first half.
  //      grid 20x64 = 1280 wgs = 5 exact rounds at 1 block/CU.
  gemm256_kernel<1, 1><<<dim3(20, 64, 1), 512, 0, stream>>>(
      x16, D_DIM, Wt, D_DIM, by, bx, (void*)y16, (void*)xb2, D_DIM, D_DIM);
  // 5. causal conv -> f16
  conv_kernel<<<dim3(5, 4096, 4), 128, 0, stream>>>(xb2, cw, cb, conv16);
  // 6+7. fused gate GEMMs + RG-LRU elementwise -> a16, nx16
  gemm_gates_kernel<<<dim3(2, 128, 10), 256, 0, stream>>>(
      conv16, D_DIM, igt, agt, igb, agb, ap, segp, a16, nx16, DH);
  // 8. chunked scan; phase C fuses h*y -> f16
  scanA_kernel<<<dim3(5, CHUNKS, 4), 256, 0, stream>>>(a16, nx16, Ac, Sc);
  scanB_kernel<<<dim3(10, 1, 4), 256, 0, stream>>>(Ac, Sc, He);
  scanC_kernel<<<dim3(5, CHUNKS, 4), 256, 0, stream>>>(a16, nx16, He, y16, hy16);
  // 9. out = (h*y) @ Wo + bo -> f32
  gemm256_kernel<0, 0><<<dim3(10, 64, 1), 512, 0, stream>>>(
      hy16, D_DIM, Wot, D_DIM, bo, nullptr, (void*)out, nullptr, D_DIM, D_DIM);
}

// Round 7
// 1349.454 us; speedup vs baseline: 1.1858x; 1.1858x over previous
//
#include <hip/hip_runtime.h>

#define D_DIM 2560
#define T_DIM 4096
#define B_DIM 4
#define H_DIM 10
#define DH 256
#define TW_DIM 4
#define M_DIM (B_DIM * T_DIM)   // 16384
#define CHUNKS 64
#define TC (T_DIM / CHUNKS)     // 64

typedef _Float16 f16;
typedef __attribute__((ext_vector_type(8))) _Float16 f16x8;
typedef __attribute__((ext_vector_type(4))) _Float16 f16x4;
typedef __attribute__((ext_vector_type(2))) _Float16 f16x2;
typedef __attribute__((ext_vector_type(4))) float f32x4;
typedef __attribute__((ext_vector_type(2))) float f32x2;

// ---------------- convert f32 -> f16 (vectorized x4) ----------------
__global__ void cvt_f16_kernel(const float* __restrict__ in, f16* __restrict__ out, long n4) {
  long i = (long)blockIdx.x * blockDim.x + threadIdx.x;
  if (i >= n4) return;
  f32x4 v = ((const f32x4*)in)[i];
  f16x4 o;
  o[0] = (f16)v[0]; o[1] = (f16)v[1]; o[2] = (f16)v[2]; o[3] = (f16)v[3];
  ((f16x4*)out)[i] = o;
}

// ---------------- transpose + convert, 3 separate square sources ----------------
__global__ void transpose_cvt3_kernel(const float* __restrict__ s0, const float* __restrict__ s1,
                                      const float* __restrict__ s2, f16* __restrict__ out,
                                      int R, int C) {
  __shared__ float tile[32][33];
  const int z = blockIdx.z;
  const float* in = (z == 0) ? s0 : ((z == 1) ? s1 : s2);
  out += (long)z * R * C;
  int c0 = blockIdx.x * 32, r0 = blockIdx.y * 32;
  int tx = threadIdx.x, ty = threadIdx.y;
  for (int i = ty; i < 32; i += 8)
    tile[i][tx] = in[(long)(r0 + i) * C + (c0 + tx)];
  __syncthreads();
  for (int i = ty; i < 32; i += 8)
    out[(long)(c0 + i) * R + (r0 + tx)] = (f16)tile[tx][i];
}

// ---------------- transpose + convert, 2 batched sources (ig, ag) ----------------
__global__ void transpose_cvt2_kernel(const float* __restrict__ sa, const float* __restrict__ sb,
                                      f16* __restrict__ out, int R, int C, int half) {
  __shared__ float tile[32][33];
  const int z = blockIdx.z;
  const float* in = (z < half) ? (sa + (long)z * R * C) : (sb + (long)(z - half) * R * C);
  out += (long)z * R * C;
  int c0 = blockIdx.x * 32, r0 = blockIdx.y * 32;
  int tx = threadIdx.x, ty = threadIdx.y;
  for (int i = ty; i < 32; i += 8)
    tile[i][tx] = in[(long)(r0 + i) * C + (c0 + tx)];
  __syncthreads();
  for (int i = ty; i < 32; i += 8)
    out[(long)(c0 + i) * R + (r0 + tx)] = (f16)tile[tx][i];
}

// ---------------- async global -> LDS, 16B per lane ----------------
__device__ __forceinline__ void async_cp16(const void* g, void* l) {
  __builtin_amdgcn_global_load_lds(
      (const __attribute__((address_space(1))) unsigned int*)g,
      (__attribute__((address_space(3))) unsigned int*)l, 16, 0, 0);
}

__device__ __forceinline__ float fast_sigmoid(float v) {
  return 1.f / (1.f + __expf(-v));
}

// =====================================================================
// 8-phase 256x256 GEMM, UNPINNED. BK=64, 2 buffers (even step->buf0, odd
// ->buf1), LDS 128KiB, 8 waves (2Mx4N), per-wave 128x64 (acc[8][4]).
// vs R4: ONE asm s_barrier per phase (8/iter, was 16); NO manual lgkmcnt
// or sched_barrier (compiler manages ds_read->MFMA waits, m97/m141);
// vmcnt(6) at phases 2/4/6/8 (was vmcnt(4) at 4/8) -> >=4-phase slack.
//
// Stage order (iter i, s=2i): ph1 A0(s+1) ph2 A1(s+1) ph3 B0(s+2)
//   ph4 B1(s+2) ph5 A0(s+2) ph6 A1(s+2) ph7 B0(s+3) ph8 B1(s+3).
// Read deadlines: A-lo(s)@ph1 B-lo(s)@ph1 B-hi(s)@ph2 A-hi(s)@ph3,
//   shifted +4 phases for s+1. Steady-state ledger (2 loads/stage,
//   vmcnt(6) leaves 3 newest stages in flight): every half-tile retires
//   at a vmcnt >=1 barrier before its first read. Prologue: A(0),B(0),
//   B(1) = 12 loads + vmcnt(4) (B(1)'s 4 stay outstanding). Tail clamps
//   write only dead/identical regions after their last-read barriers.
// Swizzle identical to R4 (measured conflicts == 0).
// =====================================================================
#define BM2 256
#define BN2 256

template<int ACT, int OUT16>
__global__ __launch_bounds__(512, 2)
void gemm256_kernel(const f16* __restrict__ A, long ldA,
                    const f16* __restrict__ Bt, long ldB,
                    const float* __restrict__ bias,
                    void* __restrict__ Cv, long ldC, int K) {
  __shared__ __attribute__((aligned(16))) f16 smh[65536];  // 128 KiB
  const int tid = threadIdx.x;
  const int wave = tid >> 6;
  const int lane = tid & 63;
  const int wm = wave >> 2;      // 0..1 -> rows wm*128..+127
  const int wn = wave & 3;       // 0..3 -> cols wn*64..+63

  // ---- XCD-aware chunked block remap (640 wgs, 640%8==0)
  const int nx_ = gridDim.x;
  const int nwg = nx_ * gridDim.y;
  int lid = blockIdx.y * nx_ + blockIdx.x;
  lid = (lid & 7) * (nwg >> 3) + (lid >> 3);
  const long bm = (long)(lid / nx_) * BM2;
  const long bn = (long)(lid % nx_) * BN2;

  // ---- staging geometry: instr covers 8 rows x 128B; wave w covers rows 16w..16w+15 (2 instr)
  const int rsub = lane >> 3;                     // 0..7
  const int gc8 = (((lane & 7) ^ rsub) & 7) * 8;  // swizzled global 16B-chunk (halfs)
  const f16* gA0 = A + (bm + wave * 16 + rsub) * ldA + gc8;
  const f16* gB0 = Bt + (bn + wave * 16 + rsub) * ldB + gc8;
  const int wls = wave * 1024;                    // lds halfs within half-tile

#define STG_A(buf, al, ko) do { \
  async_cp16(gA0 + ((al) * 128) * ldA + (ko), smh + (buf) * 32768 + (al) * 8192 + wls); \
  async_cp16(gA0 + ((al) * 128 + 8) * ldA + (ko), smh + (buf) * 32768 + (al) * 8192 + wls + 512); \
} while (0)
#define STG_B(buf, bl, ko) do { \
  async_cp16(gB0 + ((bl) * 128) * ldB + (ko), smh + (buf) * 32768 + 16384 + (bl) * 8192 + wls); \
  async_cp16(gB0 + ((bl) * 128 + 8) * ldB + (ko), smh + (buf) * 32768 + 16384 + (bl) * 8192 + wls + 512); \
} while (0)

  // ---- fragment-read geometry (reader compensates store swizzle)
  const int quad = lane >> 4, l16 = lane & 15;
  const int sw0 = ((quad ^ (l16 & 7)) & 7) * 8;        // h=0 chunk (halfs)
  const int sw1 = (((4 + quad) ^ (l16 & 7)) & 7) * 8;  // h=1 chunk
  const int aRB0 = wm * 8192 + l16 * 64;
  const int aRB1 = 32768 + aRB0;
  const int bRB0 = 16384 + (wn >> 1) * 8192 + ((wn & 1) * 64 + l16) * 64;
  const int bRB1 = 32768 + bRB0;

  f16x8 aL[4][2], aH[4][2], bF[4][2];
  f32x4 acc[8][4];
#pragma unroll
  for (int i = 0; i < 8; ++i)
#pragma unroll
    for (int j = 0; j < 4; ++j) {
      acc[i][j][0] = 0.f; acc[i][j][1] = 0.f; acc[i][j][2] = 0.f; acc[i][j][3] = 0.f;
    }

#define LD8(off) (*(const f16x8*)&smh[(off)])
#define RD_A(AX, base, off) do { _Pragma("unroll") for (int m_ = 0; m_ < 4; ++m_) { \
  AX[m_][0] = LD8((base) + (off) + m_ * 1024 + sw0); \
  AX[m_][1] = LD8((base) + (off) + m_ * 1024 + sw1); } } while (0)
#define RD_B2(base, n0) do { _Pragma("unroll") for (int n_ = 0; n_ < 2; ++n_) { \
  bF[(n0) + n_][0] = LD8((base) + ((n0) + n_) * 1024 + sw0); \
  bF[(n0) + n_][1] = LD8((base) + ((n0) + n_) * 1024 + sw1); } } while (0)
#define MM(AX, MB, N0) do { _Pragma("unroll") for (int m_ = 0; m_ < 4; ++m_) \
  _Pragma("unroll") for (int n_ = 0; n_ < 2; ++n_) \
    acc[(MB) + m_][(N0) + n_] = __builtin_amdgcn_mfma_f32_16x16x32_f16(AX[m_][1], bF[(N0) + n_][1], \
      __builtin_amdgcn_mfma_f32_16x16x32_f16(AX[m_][0], bF[(N0) + n_][0], acc[(MB) + m_][(N0) + n_], 0, 0, 0), 0, 0, 0); \
} while (0)
#define SP1 __builtin_amdgcn_s_setprio(1)
#define SP0 __builtin_amdgcn_s_setprio(0)
#define PH_BAR() asm volatile("s_barrier" ::: "memory")
#define PH_VM6() do { asm volatile("s_waitcnt vmcnt(6)" ::: "memory"); \
                      asm volatile("s_barrier" ::: "memory"); } while (0)

  const int NT = K / 64;      // 40
  const int NIT = NT / 2;     // 20

  // ---- prologue: A(0), B(0) -> buf0; B(1) -> buf1 (12 loads)
  STG_A(0, 0, 0); STG_A(0, 1, 0);
  STG_B(0, 0, 0); STG_B(0, 1, 0);
  STG_B(1, 0, 64); STG_B(1, 1, 64);
  asm volatile("s_waitcnt vmcnt(4)" ::: "memory");  // tile0 resident; B(1) in flight
  asm volatile("s_barrier" ::: "memory");

#pragma unroll 1
  for (int it = 0; it < NIT; ++it) {
    const int s = 2 * it;
    const long k1 = (long)(s + 1) * 64;                               // never clamps
    const long k2 = (long)(s + 2 < NT ? s + 2 : NT - 1) * 64;
    const long k3 = (long)(s + 3 < NT ? s + 3 : NT - 1) * 64;
    // ph1: q0 = A_lo x B_lo (buf0); stage A0(s+1)
    RD_A(aL, aRB0, 0); RD_B2(bRB0, 0); STG_A(1, 0, k1);
    SP1; MM(aL, 0, 0); SP0; PH_BAR();
    // ph2: q1 = A_lo x B_hi; stage A1(s+1); vmcnt
    RD_B2(bRB0, 2); STG_A(1, 1, k1);
    SP1; MM(aL, 0, 2); SP0; PH_VM6();
    // ph3: q2 = A_hi x B_hi; stage B0(s+2)
    RD_A(aH, aRB0, 4096); STG_B(0, 0, k2);
    SP1; MM(aH, 4, 2); SP0; PH_BAR();
    // ph4: q3 = A_hi x B_lo (regs only); stage B1(s+2); vmcnt
    STG_B(0, 1, k2);
    SP1; MM(aH, 4, 0); SP0; PH_VM6();
    // ph5-8: K-step s+1 from buf1
    RD_A(aL, aRB1, 0); RD_B2(bRB1, 0); STG_A(0, 0, k2);
    SP1; MM(aL, 0, 0); SP0; PH_BAR();
    RD_B2(bRB1, 2); STG_A(0, 1, k2);
    SP1; MM(aL, 0, 2); SP0; PH_VM6();
    RD_A(aH, aRB1, 4096); STG_B(1, 0, k3);
    SP1; MM(aH, 4, 2); SP0; PH_BAR();
    STG_B(1, 1, k3);
    SP1; MM(aH, 4, 0); SP0; PH_VM6();
  }
  asm volatile("s_waitcnt vmcnt(0)" ::: "memory");

  // ---- epilogue: C/D layout col=lane&15, row=(lane>>4)*4+reg
#pragma unroll
  for (int i = 0; i < 8; ++i) {
    const long row0 = bm + wm * 128 + i * 16 + quad * 4;
#pragma unroll
    for (int j = 0; j < 4; ++j) {
      const long colIn = bn + wn * 64 + j * 16 + l16;
      const float bv = bias[colIn];
#pragma unroll
      for (int r = 0; r < 4; ++r) {
        const long row = row0 + r;
        float v = acc[i][j][r] + bv;
        if (ACT == 1) {
          const float u = v;
          const float tt = 0.7978845608028654f * (u + 0.044715f * u * u * u);
          v = u * fast_sigmoid(2.f * tt);   // gelu tanh approx
        }
        const long cidx = row * ldC + colIn;
        if (OUT16) ((f16*)Cv)[cidx] = (f16)v;
        else       ((float*)Cv)[cidx] = v;
      }
    }
  }
#undef STG_A
#undef STG_B
#undef LD8
#undef RD_A
#undef RD_B2
#undef MM
#undef SP1
#undef SP0
#undef PH_BAR
#undef PH_VM6
}

// =====================================================================
// Fused gate GEMMs: gate_x/gate_a sigmoid + RG-LRU elementwise -> a16, nx16
// =====================================================================
#define BM 128
#define BN 128
#define BK 32

__global__ __launch_bounds__(256, 2)
void gemm_gates_kernel(const f16* __restrict__ A, long ldA,
                       const f16* __restrict__ igt, const f16* __restrict__ agt,
                       const float* __restrict__ igb, const float* __restrict__ agb,
                       const float* __restrict__ apar, const int* __restrict__ segp,
                       f16* __restrict__ aOut, f16* __restrict__ nxOut, int K) {
  __shared__ __attribute__((aligned(16))) f16 As[BM * BK];
  __shared__ __attribute__((aligned(16))) f16 B1s[BN * BK];
  __shared__ __attribute__((aligned(16))) f16 B2s[BN * BK];
  const int tid = threadIdx.x;
  const int wave = tid >> 6;
  const int lane = tid & 63;
  const int wm = wave >> 1, wn = wave & 1;
  const long bm = (long)blockIdx.y * BM;
  const long bn = (long)blockIdx.x * BN;
  const int z = blockIdx.z;
  const f16* Az = A + (long)z * DH;                  // column offset into [M,D]
  const f16* B1 = igt + (long)z * DH * DH;
  const f16* B2 = agt + (long)z * DH * DH;
  const float* b1 = igb + (long)z * DH;
  const float* b2 = agb + (long)z * DH;
  const long cColOff = (long)z * DH;

  const int sRow = wave * 32 + (lane >> 2);
  const int sCol = ((lane & 3) ^ (sRow & 3) ^ ((sRow >> 2) & 3)) * 8;  // halfs
  const f16* gA = Az + (bm + sRow) * ldA + sCol;
  const f16* gB1 = B1 + (bn + sRow) * (long)K + sCol;
  const f16* gB2 = B2 + (bn + sRow) * (long)K + sCol;
  f16* lA = As + wave * 1024;
  f16* lB1 = B1s + wave * 1024;
  f16* lB2 = B2s + wave * 1024;

  f32x4 accI[4][4], accA[4][4];
#pragma unroll
  for (int i = 0; i < 4; ++i)
#pragma unroll
    for (int j = 0; j < 4; ++j) {
      accI[i][j][0] = 0.f; accI[i][j][1] = 0.f; accI[i][j][2] = 0.f; accI[i][j][3] = 0.f;
      accA[i][j][0] = 0.f; accA[i][j][1] = 0.f; accA[i][j][2] = 0.f; accA[i][j][3] = 0.f;
    }

  const int quad = lane >> 4, l16 = lane & 15;
  const int rswz = (quad ^ (l16 & 3) ^ ((l16 >> 2) & 3)) * 8;

  for (int k0 = 0; k0 < K; k0 += BK) {
    async_cp16(gA, lA);
    async_cp16(gA + 16 * ldA, lA + 512);
    async_cp16(gB1, lB1);
    async_cp16(gB1 + 16 * (long)K, lB1 + 512);
    async_cp16(gB2, lB2);
    async_cp16(gB2 + 16 * (long)K, lB2 + 512);
    gA += BK; gB1 += BK; gB2 += BK;
    __syncthreads();
    f16x8 af[4], bf1[4], bf2[4];
#pragma unroll
    for (int i = 0; i < 4; ++i) {
      af[i]  = *(const f16x8*)&As[(wm * 64 + i * 16 + l16) * BK + rswz];
      bf1[i] = *(const f16x8*)&B1s[(wn * 64 + i * 16 + l16) * BK + rswz];
      bf2[i] = *(const f16x8*)&B2s[(wn * 64 + i * 16 + l16) * BK + rswz];
    }
#pragma unroll
    for (int i = 0; i < 4; ++i)
#pragma unroll
      for (int j = 0; j < 4; ++j) {
        accI[i][j] = __builtin_amdgcn_mfma_f32_16x16x32_f16(af[i], bf1[j], accI[i][j], 0, 0, 0);
        accA[i][j] = __builtin_amdgcn_mfma_f32_16x16x32_f16(af[i], bf2[j], accA[i][j], 0, 0, 0);
      }
    __syncthreads();
  }

#pragma unroll
  for (int i = 0; i < 4; ++i) {
    const long row0 = bm + wm * 64 + i * 16 + quad * 4;
#pragma unroll
    for (int j = 0; j < 4; ++j) {
      const long colIn = bn + wn * 64 + j * 16 + l16;
      const long colG = cColOff + colIn;
      const float bv1 = b1[colIn];
      const float bv2 = b2[colIn];
      const float sp = log1pf(__expf(apar[colG]));
#pragma unroll
      for (int r = 0; r < 4; ++r) {
        const long row = row0 + r;
        const float gx = fast_sigmoid(accI[i][j][r] + bv1);
        const float ga = fast_sigmoid(accA[i][j][r] + bv2);
        const float log_a = -8.f * ga * sp;
        float a = __expf(log_a);
        float mult = sqrtf(fmaxf(1.f - __expf(2.f * log_a), 0.f));
        if (segp[row] == 0) { a = 0.f; mult = 1.f; }
        const long cidx = row * D_DIM + colG;
        const float cv = (float)A[row * ldA + colG];   // conv value
        aOut[cidx] = (f16)a;
        nxOut[cidx] = (f16)(cv * gx * mult);
      }
    }
  }
}

// ---------------- causal depthwise conv (TW=4), f16 in -> f16 out, x4 ----------------
__global__ void conv_kernel(const f16* __restrict__ xb, const float* __restrict__ cw,
                            const float* __restrict__ cb, f16* __restrict__ out) {
  const int d4 = blockIdx.x * 128 + threadIdx.x;  // over D/4 = 640
  const int t = blockIdx.y;
  const int b = blockIdx.z;
  const long idx4 = ((long)b * T_DIM + t) * (D_DIM / 4) + d4;
  f32x4 acc = ((const f32x4*)cb)[d4];
#pragma unroll
  for (int i = 0; i < TW_DIM; ++i) {
    const int tt = t - (TW_DIM - 1) + i;
    if (tt >= 0) {
      f16x4 xv = ((const f16x4*)xb)[idx4 + (long)(i - (TW_DIM - 1)) * (D_DIM / 4)];
      f32x4 w = ((const f32x4*)cw)[i * (D_DIM / 4) + d4];
      acc[0] += w[0] * (float)xv[0];
      acc[1] += w[1] * (float)xv[1];
      acc[2] += w[2] * (float)xv[2];
      acc[3] += w[3] * (float)xv[3];
    }
  }
  f16x4 o;
  o[0] = (f16)acc[0]; o[1] = (f16)acc[1]; o[2] = (f16)acc[2]; o[3] = (f16)acc[3];
  ((f16x4*)out)[idx4] = o;
}

// ---------------- chunked scan: h_t = a_t h_{t-1} + x_t (x2 vectorized) ----------------
__global__ void scanA_kernel(const f16* __restrict__ a16, const f16* __restrict__ nx16,
                             float* __restrict__ Ac, float* __restrict__ Sc) {
  const int d2 = blockIdx.x * 256 + threadIdx.x;  // over D/2 = 1280
  const int c = blockIdx.y;
  const int b = blockIdx.z;
  long base2 = ((long)b * T_DIM + (long)c * TC) * (D_DIM / 2) + d2;
  float Ap0 = 1.f, Ap1 = 1.f, S0 = 0.f, S1 = 0.f;
  for (int t = 0; t < TC; ++t) {
    f16x2 av = ((const f16x2*)a16)[base2];
    f16x2 xv = ((const f16x2*)nx16)[base2];
    S0 = (float)av[0] * S0 + (float)xv[0];
    S1 = (float)av[1] * S1 + (float)xv[1];
    Ap0 *= (float)av[0];
    Ap1 *= (float)av[1];
    base2 += D_DIM / 2;
  }
  const long cidx2 = ((long)b * CHUNKS + c) * (D_DIM / 2) + d2;
  f32x2 av_; av_[0] = Ap0; av_[1] = Ap1;
  f32x2 sv_; sv_[0] = S0; sv_[1] = S1;
  ((f32x2*)Ac)[cidx2] = av_;
  ((f32x2*)Sc)[cidx2] = sv_;
}

__global__ void scanB_kernel(const float* __restrict__ Ac, const float* __restrict__ Sc,
                             float* __restrict__ He) {
  const int d = blockIdx.x * 256 + threadIdx.x;
  const int b = blockIdx.z;
  float h = 0.f;
  for (int c = 0; c < CHUNKS; ++c) {
    const long cidx = ((long)b * CHUNKS + c) * D_DIM + d;
    He[cidx] = h;  // h at entry of chunk c
    h = Ac[cidx] * h + Sc[cidx];
  }
}

__global__ void scanC_kernel(const f16* __restrict__ a16, const f16* __restrict__ nx16,
                             const float* __restrict__ He, const f16* __restrict__ y16,
                             f16* __restrict__ hy16) {
  const int d2 = blockIdx.x * 256 + threadIdx.x;
  const int c = blockIdx.y;
  const int b = blockIdx.z;
  long base2 = ((long)b * T_DIM + (long)c * TC) * (D_DIM / 2) + d2;
  f32x2 hv = ((const f32x2*)He)[((long)b * CHUNKS + c) * (D_DIM / 2) + d2];
  float h0 = hv[0], h1 = hv[1];
  for (int t = 0; t < TC; ++t) {
    f16x2 av = ((const f16x2*)a16)[base2];
    f16x2 xv = ((const f16x2*)nx16)[base2];
    f16x2 yv = ((const f16x2*)y16)[base2];
    h0 = (float)av[0] * h0 + (float)xv[0];
    h1 = (float)av[1] * h1 + (float)xv[1];
    f16x2 o;
    o[0] = (f16)(h0 * (float)yv[0]);
    o[1] = (f16)(h1 * (float)yv[1]);
    ((f16x2*)hy16)[base2] = o;
    base2 += D_DIM / 2;
  }
}

// ---------------- launch ----------------
extern "C" void kernel_launch(void* const* d_in, const int* in_sizes, int n_in,
                              void* d_out, int out_size, void* d_ws, size_t ws_size,
                              hipStream_t stream) {
  const float* x   = (const float*)d_in[0];
  const int*   segp= (const int*)d_in[1];
  const float* Wy  = (const float*)d_in[2];
  const float* by  = (const float*)d_in[3];
  const float* Wx  = (const float*)d_in[4];
  const float* bx  = (const float*)d_in[5];
  const float* cw  = (const float*)d_in[6];
  const float* cb  = (const float*)d_in[7];
  const float* ap  = (const float*)d_in[8];
  const float* igw = (const float*)d_in[9];
  const float* igb = (const float*)d_in[10];
  const float* agw = (const float*)d_in[11];
  const float* agb = (const float*)d_in[12];
  const float* Wo  = (const float*)d_in[13];
  const float* bo  = (const float*)d_in[14];
  float* out = (float*)d_out;
  char* ws = (char*)d_ws;

  const long MD = (long)M_DIM * D_DIM;  // 41,943,040
  f16*   x16    = (f16*)(ws + 0);          // dead after GEMMs 1,2 -> a16
  f16*   a16    = (f16*)(ws + 0);
  f16*   y16    = (f16*)(ws + MD * 2);     // live until scanC
  f16*   xb2    = (f16*)(ws + MD * 4);     // dead after conv -> hy16
  f16*   hy16   = (f16*)(ws + MD * 4);
  f16*   conv16 = (f16*)(ws + MD * 6);     // live until gates epilogue
  f16*   nx16   = (f16*)(ws + MD * 8);
  long off = MD * 10;
  f16* Wt  = (f16*)(ws + off); off += 3L * D_DIM * D_DIM * 2;   // Wyt,Wxt,Wot contiguous
  f16* igagt = (f16*)(ws + off); off += 20L * DH * DH * 2;      // igt(10) then agt(10)
  float* Ac = (float*)(ws + off); off += (long)B_DIM * CHUNKS * D_DIM * 4;
  float* Sc = (float*)(ws + off); off += (long)B_DIM * CHUNKS * D_DIM * 4;
  float* He = (float*)(ws + off); off += (long)B_DIM * CHUNKS * D_DIM * 4;
  f16* Wyt = Wt;
  f16* Wxt = Wt + (long)D_DIM * D_DIM;
  f16* Wot = Wt + 2L * D_DIM * D_DIM;
  f16* igt = igagt;
  f16* agt = igagt + 10L * DH * DH;

  dim3 tb(32, 8);
  // 1. x -> f16
  cvt_f16_kernel<<<dim3((unsigned)(MD / 4 / 256)), 256, 0, stream>>>(x, x16, MD / 4);
  // 2. weight transposes -> [N,K] f16
  transpose_cvt3_kernel<<<dim3(80, 80, 3), tb, 0, stream>>>(Wy, Wx, Wo, Wt, D_DIM, D_DIM);
  transpose_cvt2_kernel<<<dim3(8, 8, 20), tb, 0, stream>>>(igw, agw, igagt, DH, DH, 10);
  // 3. y = gelu(x @ Wy + by) -> f16
  gemm256_kernel<1, 1><<<dim3(10, 64, 1), 512, 0, stream>>>(
      x16, D_DIM, Wyt, D_DIM, by, (void*)y16, D_DIM, D_DIM);
  // 4. xb = x @ Wx + bx -> f16
  gemm256_kernel<0, 1><<<dim3(10, 64, 1), 512, 0, stream>>>(
      x16, D_DIM, Wxt, D_DIM, bx, (void*)xb2, D_DIM, D_DIM);
  // 5. causal conv -> f16
  conv_kernel<<<dim3(5, 4096, 4), 128, 0, stream>>>(xb2, cw, cb, conv16);
  // 6+7. fused gate GEMMs + RG-LRU elementwise -> a16, nx16
  gemm_gates_kernel<<<dim3(2, 128, 10), 256, 0, stream>>>(
      conv16, D_DIM, igt, agt, igb, agb, ap, segp, a16, nx16, DH);
  // 8. chunked scan; phase C fuses h*y -> f16
  scanA_kernel<<<dim3(5, CHUNKS, 4), 256, 0, stream>>>(a16, nx16, Ac, Sc);
  scanB_kernel<<<dim3(10, 1, 4), 256, 0, stream>>>(Ac, Sc, He);
  scanC_kernel<<<dim3(5, CHUNKS, 4), 256, 0, stream>>>(a16, nx16, He, y16, hy16);
  // 9. out = (h*y) @ Wo + bo -> f32
  gemm256_kernel<0, 0><<<dim3(10, 64, 1), 512, 0, stream>>>(
      hy16, D_DIM, Wot, D_DIM, bo, (void*)out, D_DIM, D_DIM);
}